// Round 3
// baseline (3357.626 us; speedup 1.0000x reference)
//
#include <hip/hip_runtime.h>
#include <cstddef>
#include <cstdint>

#define B_    8
#define L_    4096
#define DIN_  256
#define H_    256
#define DOUT_ 256
#define NL_   4
#define N_    64

typedef __attribute__((ext_vector_type(8))) __bf16 bf16x8;
typedef __attribute__((ext_vector_type(4))) __bf16 bf16x4;
typedef __attribute__((ext_vector_type(4))) float f32x4;

__device__ __forceinline__ float sigmoid_f(float v) {
    return 1.f / (1.f + __expf(-v));
}
// jax.nn.gelu default (approximate=True): 0.5x(1+tanh(sqrt(2/pi)(x+0.044715x^3)))
__device__ __forceinline__ float gelu_f(float y) {
    float q = 0.7978845608028654f * (y + 0.044715f * y * y * y);
    float e = __expf(2.f * q);          // tanh(q) = 1 - 2/(e^{2q}+1); saturates correctly
    float th = 1.f - 2.f / (e + 1.f);
    return 0.5f * y * (1.f + th);
}

// ---------------------------------------------------------------------------
// Per-layer constants: w = exp(dtA), Ct2 = 2*C*expm1(dtA)/A, K[m] = Re sum_n Ct2 w^m
// Kt stored padded: Kt[h*128 + x] = (x>=63) ? K[x-63] : 0   (x=127 -> 0)
// ---------------------------------------------------------------------------
__global__ __launch_bounds__(64) void precompute_kernel(
    const float* __restrict__ log_dt, const float* __restrict__ A_re_log,
    const float* __restrict__ A_im, const float* __restrict__ C_re,
    const float* __restrict__ C_im, float* __restrict__ Wt,
    float* __restrict__ Ct2t, float* __restrict__ Kt, int layer)
{
    const int h = blockIdx.x;
    const int n = threadIdx.x;                       // 0..63
    const int idx = (layer * H_ + h) * N_ + n;
    float dt  = __expf(log_dt[layer * H_ + h]);
    float Are = -__expf(A_re_log[idx]);
    float Aim = A_im[idx];
    float ar = Are * dt, ai = Aim * dt;              // dtA
    float ea = __expf(ar);
    float cb = cosf(ai), sb = sinf(ai);
    float wr = ea * cb, wi = ea * sb;                // w = exp(dtA)
    float em1 = expm1f(ar);
    float sh  = sinf(0.5f * ai);
    float emr = em1 * cb - 2.f * sh * sh;
    float emi = ea * sb;
    float Cr = C_re[idx], Ci = C_im[idx];
    float nr = Cr * emr - Ci * emi;
    float ni = Cr * emi + Ci * emr;
    float den = Are * Are + Aim * Aim;
    float inv = 2.f / den;                           // fold factor 2 into Ct2
    float c2r = (nr * Are + ni * Aim) * inv;
    float c2i = (ni * Are - nr * Aim) * inv;
    ((float2*)Wt)[h * N_ + n]   = make_float2(wr, wi);
    ((float2*)Ct2t)[h * N_ + n] = make_float2(c2r, c2i);

    float pr = c2r, pi = c2i;
    for (int m = 0; m < 64; ++m) {
        float s = pr;
        for (int off = 32; off; off >>= 1) s += __shfl_xor(s, off);
        if (n == 0) Kt[h * 128 + 63 + m] = s;
        float t2 = pr * wr - pi * wi;
        pi = pr * wi + pi * wr;
        pr = t2;
    }
    if (n < 63) Kt[h * 128 + n] = 0.f;
    if (n == 63) Kt[h * 128 + 127] = 0.f;
}

// ---------------------------------------------------------------------------
// Chunked exact SSM scan + D*u + GELU.  One block per (b,h); 4 waves.
// ---------------------------------------------------------------------------
__global__ __launch_bounds__(256) void scan_kernel(
    const float* __restrict__ XR, const float* __restrict__ XI,
    float* __restrict__ ZR, float* __restrict__ ZI,
    const float* __restrict__ Wt, const float* __restrict__ Ct2t,
    const float* __restrict__ Kt, const float* __restrict__ Dp)
{
    const int bh = blockIdx.x;                 // B*H
    const int b = bh >> 8, h = bh & 255;
    const int t = threadIdx.x;
    const int wid = t >> 6, lane = t & 63;
    const int ch = wid >> 1;
    const bool is_out = ((wid & 1) == 0);
    const float* U = ch ? XI : XR;
    float* Z = ch ? ZI : ZR;
    const size_t rbase = ((size_t)b * H_ + h) * (size_t)L_;
    const float* row = U + rbase;
    float* zrow = Z + rbase;

    __shared__ __align__(16) float Kp[128];
    __shared__ __align__(16) float ubuf[2][2][64];
    __shared__ __align__(16) float2 gbuf[2][2][64];

    if (t < 128) Kp[t] = Kt[h * 128 + t];
    if (t < 64) {
        gbuf[0][0][t] = make_float2(0.f, 0.f);
        gbuf[1][0][t] = make_float2(0.f, 0.f);
    }

    float pr[64], pi[64];                      // out waves: w_n^{lane+1}
    float wr = 0.f, wi = 0.f, cr = 0.f, ci = 0.f, Sr = 0.f, Si = 0.f;
    const float Dh = Dp[h];
    const float2* Wp = (const float2*)Wt + (size_t)h * N_;

    if (is_out) {
        #pragma unroll
        for (int n = 0; n < 64; ++n) {
            float2 w = Wp[n];
            float rr = 1.f, ri = 0.f, br2 = w.x, bi2 = w.y;
            int e = lane + 1;                  // 1..64
            #pragma unroll
            for (int bit = 0; bit < 7; ++bit) {
                float tr = rr * br2 - ri * bi2;
                float ti = rr * bi2 + ri * br2;
                bool take = ((e >> bit) & 1) != 0;
                rr = take ? tr : rr;
                ri = take ? ti : ri;
                float s2 = br2 * br2 - bi2 * bi2;
                bi2 = 2.f * br2 * bi2;
                br2 = s2;
            }
            pr[n] = rr; pi[n] = ri;
        }
    } else {
        float2 w = Wp[lane];
        wr = w.x; wi = w.y;
        float2 c2 = ((const float2*)Ct2t)[(size_t)h * N_ + lane];
        cr = c2.x; ci = c2.y;
        ubuf[ch][0][lane] = row[lane];         // prologue: chunk 0
    }
    __syncthreads();

    int cur = 0;
    for (int c = 0; c < 64; ++c) {
        const int t0 = c * 64;
        if (is_out) {
            float acc = 0.f;
            const float4* up = (const float4*)&ubuf[ch][cur][0];
            #pragma unroll
            for (int j4 = 0; j4 < 16; ++j4) {  // causal conv, Kp zero-pad masks j>l
                float4 u4 = up[j4];
                int kb = lane + 63 - 4 * j4;
                acc += Kp[kb] * u4.x;
                acc += Kp[kb - 1] * u4.y;
                acc += Kp[kb - 2] * u4.z;
                acc += Kp[kb - 3] * u4.w;
            }
            const float4* gp = (const float4*)&gbuf[ch][cur][0];
            #pragma unroll
            for (int n2 = 0; n2 < 32; ++n2) {  // injection: Re sum_n g_n w^{l+1}
                float4 g2 = gp[n2];
                acc += g2.x * pr[2 * n2]     - g2.y * pi[2 * n2];
                acc += g2.z * pr[2 * n2 + 1] - g2.w * pi[2 * n2 + 1];
            }
            float uval = ubuf[ch][cur][lane];
            zrow[t0 + lane] = gelu_f(acc + Dh * uval);
        } else {
            float unext = 0.f;
            if (c < 63) unext = row[t0 + 64 + lane];
            const float* ub = &ubuf[ch][cur][0];
            #pragma unroll
            for (int j = 0; j < 64; ++j) {     // Horner state update (exact)
                float u = ub[j];
                float trr = wr * Sr - wi * Si + u;
                Si = wr * Si + wi * Sr;
                Sr = trr;
            }
            gbuf[ch][cur ^ 1][lane] = make_float2(cr * Sr - ci * Si, cr * Si + ci * Sr);
            ubuf[ch][cur ^ 1][lane] = unext;
        }
        __syncthreads();
        cur ^= 1;
    }
}

// ---------------------------------------------------------------------------
// Encoder: complex linear (B,L,DIN,2) -> XR,XI in (B,H,L).  128(l) x 64(h) x 16(k)
// ---------------------------------------------------------------------------
__global__ __launch_bounds__(256) void enc_gemm(
    const float* __restrict__ x, const float* __restrict__ Wr,
    const float* __restrict__ Wi, const float* __restrict__ br,
    const float* __restrict__ bi, float* __restrict__ XR, float* __restrict__ XI)
{
    const int nb = blockIdx.x, bb = blockIdx.y, hb = blockIdx.z;
    __shared__ float2 As[16][130];
    __shared__ float2 Bs[16][66];
    const int t = threadIdx.x, tx = t & 15, ty = t >> 4;
    float aR[8][4] = {}, aI[8][4] = {};
    const float* xb = x + ((size_t)bb * L_ + nb * 128) * DIN_ * 2;
    const float* wrb = Wr + (size_t)hb * 64 * DIN_;
    const float* wib = Wi + (size_t)hb * 64 * DIN_;
    for (int k0 = 0; k0 < DIN_; k0 += 16) {
        {
            int r = t >> 1, kq = (t & 1) * 8;
            const float* p = xb + (size_t)r * DIN_ * 2 + (k0 + kq) * 2;
            float4 a0 = *(const float4*)(p);
            float4 a1 = *(const float4*)(p + 4);
            float4 a2 = *(const float4*)(p + 8);
            float4 a3 = *(const float4*)(p + 12);
            As[kq + 0][r] = make_float2(a0.x, a0.y);
            As[kq + 1][r] = make_float2(a0.z, a0.w);
            As[kq + 2][r] = make_float2(a1.x, a1.y);
            As[kq + 3][r] = make_float2(a1.z, a1.w);
            As[kq + 4][r] = make_float2(a2.x, a2.y);
            As[kq + 5][r] = make_float2(a2.z, a2.w);
            As[kq + 6][r] = make_float2(a3.x, a3.y);
            As[kq + 7][r] = make_float2(a3.z, a3.w);
        }
        {
            int j = t >> 2, kq = (t & 3) * 4;
            float4 w4 = *(const float4*)(wrb + (size_t)j * DIN_ + k0 + kq);
            float4 v4 = *(const float4*)(wib + (size_t)j * DIN_ + k0 + kq);
            Bs[kq + 0][j] = make_float2(w4.x, v4.x);
            Bs[kq + 1][j] = make_float2(w4.y, v4.y);
            Bs[kq + 2][j] = make_float2(w4.z, v4.z);
            Bs[kq + 3][j] = make_float2(w4.w, v4.w);
        }
        __syncthreads();
        #pragma unroll
        for (int kk = 0; kk < 16; ++kk) {
            float2 af[8], bf[4];
            #pragma unroll
            for (int r2 = 0; r2 < 8; ++r2) af[r2] = As[kk][ty * 8 + r2];
            #pragma unroll
            for (int c2 = 0; c2 < 4; ++c2) bf[c2] = Bs[kk][tx * 4 + c2];
            #pragma unroll
            for (int r2 = 0; r2 < 8; ++r2)
                #pragma unroll
                for (int c2 = 0; c2 < 4; ++c2) {
                    aR[r2][c2] += af[r2].x * bf[c2].x - af[r2].y * bf[c2].y;
                    aI[r2][c2] += af[r2].x * bf[c2].y + af[r2].y * bf[c2].x;
                }
        }
        __syncthreads();
    }
    #pragma unroll
    for (int c2 = 0; c2 < 4; ++c2) {
        int h = hb * 64 + tx * 4 + c2;
        float vr = br[h], vi = bi[h];
        size_t ro = ((size_t)bb * H_ + h) * L_ + nb * 128 + ty * 8;
        *(float4*)(XR + ro)     = make_float4(aR[0][c2] + vr, aR[1][c2] + vr, aR[2][c2] + vr, aR[3][c2] + vr);
        *(float4*)(XR + ro + 4) = make_float4(aR[4][c2] + vr, aR[5][c2] + vr, aR[6][c2] + vr, aR[7][c2] + vr);
        *(float4*)(XI + ro)     = make_float4(aI[0][c2] + vi, aI[1][c2] + vi, aI[2][c2] + vi, aI[3][c2] + vi);
        *(float4*)(XI + ro + 4) = make_float4(aI[4][c2] + vi, aI[5][c2] + vi, aI[6][c2] + vi, aI[7][c2] + vi);
    }
}

// ---------------------------------------------------------------------------
// Fused GLU GEMM on matrix cores (split-bf16, 3-term: hh + hl + lh).
// C[m,l] = sum_h W[m,h] Z[h,l]; tile BM=128 (rows 0..63 = v1-half rows
// mb*64.., rows 64..127 = v2-half rows 256+mb*64..), BN=128, BK=32.
// 4 waves; wave w owns m-tiles {w, w+4} x all 8 n-tiles.
// A (W) staged natural [m][k]; B (Z) staged TRANSPOSED [l][k] via packed
// ds_write_b64.  Row stride 40 elems (80 B = 5x16 B: b128-aligned, ~2-way).
// Epilogue: v1/v2 pair in-thread -> g = (v1+b1)*sigmoid(v2+b2) -> G (B,H,L).
// ---------------------------------------------------------------------------
#define LDST 40
__global__ __launch_bounds__(256) void glu_gemm_mfma(
    const float* __restrict__ Wm, const float* __restrict__ bias,
    const float* __restrict__ Zin, float* __restrict__ G)
{
    const int nb = blockIdx.x, bb = blockIdx.y, mb = blockIdx.z;
    __shared__ __align__(16) __bf16 Ah[128][LDST];
    __shared__ __align__(16) __bf16 Al[128][LDST];
    __shared__ __align__(16) __bf16 Bh[128][LDST];
    __shared__ __align__(16) __bf16 Bl[128][LDST];
    const int t = threadIdx.x;
    const int w = t >> 6, lane = t & 63;

    f32x4 acc1[8], acc2[8];
    #pragma unroll
    for (int i = 0; i < 8; ++i) { acc1[i] = (f32x4)(0.f); acc2[i] = (f32x4)(0.f); }

    // staging assignments
    const int ar = t >> 1;                     // A row 0..127
    const int ak = (t & 1) * 16;               // k offset 0 / 16
    const int wrow = (ar < 64) ? (mb * 64 + ar) : (256 + mb * 64 + (ar - 64));
    const float* Aptr = Wm + (size_t)wrow * 256 + ak;
    const int blg = (t & 31) * 4;              // 4 consecutive l
    const int bkg = (t >> 5) * 4;              // 4 consecutive k
    const float* Bptr = Zin + ((size_t)bb * H_ + bkg) * L_ + nb * 128 + blg;

    const int frow = lane & 15;                // fragment free-dim index
    const int kfrag = (lane >> 4) * 8;         // fragment k-chunk (same for A & B)

    for (int k0 = 0; k0 < 256; k0 += 32) {
        // ---- stage A (W): 16 fp32 -> hi/lo bf16, 4x ds_write_b128
        {
            const float* p = Aptr + k0;
            float4 a0 = *(const float4*)(p);
            float4 a1 = *(const float4*)(p + 4);
            float4 a2 = *(const float4*)(p + 8);
            float4 a3 = *(const float4*)(p + 12);
            float v[16] = { a0.x,a0.y,a0.z,a0.w, a1.x,a1.y,a1.z,a1.w,
                            a2.x,a2.y,a2.z,a2.w, a3.x,a3.y,a3.z,a3.w };
            bf16x8 h0, l0, h1, l1;
            #pragma unroll
            for (int i = 0; i < 8; ++i) {
                __bf16 hh = (__bf16)v[i];
                h0[i] = hh; l0[i] = (__bf16)(v[i] - (float)hh);
                __bf16 h2 = (__bf16)v[8 + i];
                h1[i] = h2; l1[i] = (__bf16)(v[8 + i] - (float)h2);
            }
            *(bf16x8*)&Ah[ar][ak]     = h0;
            *(bf16x8*)&Ah[ar][ak + 8] = h1;
            *(bf16x8*)&Al[ar][ak]     = l0;
            *(bf16x8*)&Al[ar][ak + 8] = l1;
        }
        // ---- stage B (Z) transposed: [l][k], packed b64 writes
        {
            const float* p = Bptr + (size_t)k0 * L_;
            float4 z0 = *(const float4*)(p);
            float4 z1 = *(const float4*)(p + L_);
            float4 z2 = *(const float4*)(p + 2 * L_);
            float4 z3 = *(const float4*)(p + 3 * L_);
            float c0[4] = { z0.x, z1.x, z2.x, z3.x };
            float c1[4] = { z0.y, z1.y, z2.y, z3.y };
            float c2[4] = { z0.z, z1.z, z2.z, z3.z };
            float c3[4] = { z0.w, z1.w, z2.w, z3.w };
            float* cols[4] = { c0, c1, c2, c3 };
            #pragma unroll
            for (int i = 0; i < 4; ++i) {
                bf16x4 hv, lv;
                #pragma unroll
                for (int q = 0; q < 4; ++q) {
                    __bf16 hh = (__bf16)cols[i][q];
                    hv[q] = hh; lv[q] = (__bf16)(cols[i][q] - (float)hh);
                }
                *(bf16x4*)&Bh[blg + i][bkg] = hv;
                *(bf16x4*)&Bl[blg + i][bkg] = lv;
            }
        }
        __syncthreads();
        // ---- fragments + MFMA
        bf16x8 a1h = *(const bf16x8*)&Ah[w * 16 + frow][kfrag];
        bf16x8 a1l = *(const bf16x8*)&Al[w * 16 + frow][kfrag];
        bf16x8 a2h = *(const bf16x8*)&Ah[64 + w * 16 + frow][kfrag];
        bf16x8 a2l = *(const bf16x8*)&Al[64 + w * 16 + frow][kfrag];
        #pragma unroll
        for (int nt = 0; nt < 8; ++nt) {
            bf16x8 bh = *(const bf16x8*)&Bh[nt * 16 + frow][kfrag];
            bf16x8 bl = *(const bf16x8*)&Bl[nt * 16 + frow][kfrag];
            acc1[nt] = __builtin_amdgcn_mfma_f32_16x16x32_bf16(a1h, bh, acc1[nt], 0, 0, 0);
            acc1[nt] = __builtin_amdgcn_mfma_f32_16x16x32_bf16(a1h, bl, acc1[nt], 0, 0, 0);
            acc1[nt] = __builtin_amdgcn_mfma_f32_16x16x32_bf16(a1l, bh, acc1[nt], 0, 0, 0);
            acc2[nt] = __builtin_amdgcn_mfma_f32_16x16x32_bf16(a2h, bh, acc2[nt], 0, 0, 0);
            acc2[nt] = __builtin_amdgcn_mfma_f32_16x16x32_bf16(a2h, bl, acc2[nt], 0, 0, 0);
            acc2[nt] = __builtin_amdgcn_mfma_f32_16x16x32_bf16(a2l, bh, acc2[nt], 0, 0, 0);
        }
        __syncthreads();
    }

    // ---- epilogue: pair v1 (acc1) with v2 (acc2), gate, store
    const int mloc = w * 16 + (lane >> 4) * 4;     // + r
    float b1v[4], b2v[4];
    #pragma unroll
    for (int r = 0; r < 4; ++r) {
        b1v[r] = bias[mb * 64 + mloc + r];
        b2v[r] = bias[256 + mb * 64 + mloc + r];
    }
    #pragma unroll
    for (int nt = 0; nt < 8; ++nt) {
        #pragma unroll
        for (int r = 0; r < 4; ++r) {
            float v1 = acc1[nt][r] + b1v[r];
            float v2 = acc2[nt][r] + b2v[r];
            int m = mb * 64 + mloc + r;
            size_t off = ((size_t)bb * H_ + m) * L_ + nb * 128 + nt * 16 + frow;
            G[off] = v1 * sigmoid_f(v2);
        }
    }
}

// ---------------------------------------------------------------------------
// Residual + channel LayerNorm (in-place update of X); G already gated.
// ---------------------------------------------------------------------------
__global__ __launch_bounds__(256) void act_ln(
    const float* __restrict__ G, float* __restrict__ X,
    const float* __restrict__ lnw, const float* __restrict__ lnb)
{
    const int lt = blockIdx.x, b = blockIdx.y;
    __shared__ float tile[256][33];
    __shared__ float pm[8][32], pv[8][32];
    __shared__ float mArr[32], rsArr[32];
    const int t = threadIdx.x, c2 = t & 31, q = t >> 5;
    const size_t xb = ((size_t)b * H_) * L_ + lt * 32 + c2;
    float s1 = 0.f, s2 = 0.f;
    #pragma unroll 4
    for (int r = 0; r < 32; ++r) {
        int g = q * 32 + r;
        float gv = G[xb + (size_t)g * L_];
        float xv = X[xb + (size_t)g * L_];
        float val = xv + gv;
        tile[g][c2] = val;
        s1 += val; s2 += val * val;
    }
    pm[q][c2] = s1; pv[q][c2] = s2;
    __syncthreads();
    if (t < 32) {
        float m = 0.f, v = 0.f;
        #pragma unroll
        for (int qq = 0; qq < 8; ++qq) { m += pm[qq][t]; v += pv[qq][t]; }
        m *= (1.f / 256.f);
        v = v * (1.f / 256.f) - m * m;
        mArr[t] = m;
        rsArr[t] = rsqrtf(v + 1e-5f);
    }
    __syncthreads();
    float mC = mArr[c2], rC = rsArr[c2];
    #pragma unroll 4
    for (int r = 0; r < 32; ++r) {
        int g = q * 32 + r;
        float val = tile[g][c2];
        X[xb + (size_t)g * L_] = (val - mC) * rC * lnw[g] + lnb[g];
    }
}

// ---------------------------------------------------------------------------
// Decoder: complex linear from (B,H,L) x2 -> out (B,L,DOUT,2)
// ---------------------------------------------------------------------------
__global__ __launch_bounds__(256) void dec_gemm(
    const float* __restrict__ XR, const float* __restrict__ XI,
    const float* __restrict__ Wr, const float* __restrict__ Wi,
    const float* __restrict__ br, const float* __restrict__ bi,
    float* __restrict__ out)
{
    const int nb = blockIdx.x, bb = blockIdx.y, ob = blockIdx.z;
    __shared__ float2 As[16][130];
    __shared__ float2 Bs[16][66];
    const int t = threadIdx.x, tx = t & 15, ty = t >> 4;
    float aR[8][4] = {}, aI[8][4] = {};
    for (int k0 = 0; k0 < H_; k0 += 16) {
        {
            int kr = t >> 4, lq = (t & 15) * 8;
            const float* p1 = XR + ((size_t)bb * H_ + k0 + kr) * L_ + nb * 128 + lq;
            const float* p2 = XI + ((size_t)bb * H_ + k0 + kr) * L_ + nb * 128 + lq;
            float4 r0 = *(const float4*)p1, r1 = *(const float4*)(p1 + 4);
            float4 i0 = *(const float4*)p2, i1 = *(const float4*)(p2 + 4);
            As[kr][lq + 0] = make_float2(r0.x, i0.x);
            As[kr][lq + 1] = make_float2(r0.y, i0.y);
            As[kr][lq + 2] = make_float2(r0.z, i0.z);
            As[kr][lq + 3] = make_float2(r0.w, i0.w);
            As[kr][lq + 4] = make_float2(r1.x, i1.x);
            As[kr][lq + 5] = make_float2(r1.y, i1.y);
            As[kr][lq + 6] = make_float2(r1.z, i1.z);
            As[kr][lq + 7] = make_float2(r1.w, i1.w);
        }
        {
            int j = t >> 2, kq = (t & 3) * 4;
            float4 w4 = *(const float4*)(Wr + (size_t)(ob * 64 + j) * H_ + k0 + kq);
            float4 v4 = *(const float4*)(Wi + (size_t)(ob * 64 + j) * H_ + k0 + kq);
            Bs[kq + 0][j] = make_float2(w4.x, v4.x);
            Bs[kq + 1][j] = make_float2(w4.y, v4.y);
            Bs[kq + 2][j] = make_float2(w4.z, v4.z);
            Bs[kq + 3][j] = make_float2(w4.w, v4.w);
        }
        __syncthreads();
        #pragma unroll
        for (int kk = 0; kk < 16; ++kk) {
            float2 af[8], bf[4];
            #pragma unroll
            for (int r2 = 0; r2 < 8; ++r2) af[r2] = As[kk][ty * 8 + r2];
            #pragma unroll
            for (int c2 = 0; c2 < 4; ++c2) bf[c2] = Bs[kk][tx * 4 + c2];
            #pragma unroll
            for (int r2 = 0; r2 < 8; ++r2)
                #pragma unroll
                for (int c2 = 0; c2 < 4; ++c2) {
                    aR[r2][c2] += af[r2].x * bf[c2].x - af[r2].y * bf[c2].y;
                    aI[r2][c2] += af[r2].x * bf[c2].y + af[r2].y * bf[c2].x;
                }
        }
        __syncthreads();
    }
    float brv[4], biv[4];
    #pragma unroll
    for (int c2 = 0; c2 < 4; ++c2) {
        brv[c2] = br[ob * 64 + tx * 4 + c2];
        biv[c2] = bi[ob * 64 + tx * 4 + c2];
    }
    #pragma unroll
    for (int r2 = 0; r2 < 8; ++r2) {
        int l = nb * 128 + ty * 8 + r2;
        size_t ro = (((size_t)bb * L_ + l) * DOUT_ + ob * 64 + tx * 4) * 2;
        *(float4*)(out + ro)     = make_float4(aR[r2][0] + brv[0], aI[r2][0] + biv[0],
                                               aR[r2][1] + brv[1], aI[r2][1] + biv[1]);
        *(float4*)(out + ro + 4) = make_float4(aR[r2][2] + brv[2], aI[r2][2] + biv[2],
                                               aR[r2][3] + brv[3], aI[r2][3] + biv[3]);
    }
}

// ---------------------------------------------------------------------------
extern "C" void kernel_launch(void* const* d_in, const int* in_sizes, int n_in,
                              void* d_out, int out_size, void* d_ws, size_t ws_size,
                              hipStream_t stream)
{
    (void)in_sizes; (void)n_in; (void)out_size; (void)ws_size;
    const float* x       = (const float*)d_in[0];
    const float* enc_Wr  = (const float*)d_in[1];
    const float* enc_Wi  = (const float*)d_in[2];
    const float* enc_br  = (const float*)d_in[3];
    const float* enc_bi  = (const float*)d_in[4];
    const float* log_dt  = (const float*)d_in[5];
    const float* A_re_log= (const float*)d_in[6];
    const float* A_im    = (const float*)d_in[7];
    const float* C_re    = (const float*)d_in[8];
    const float* C_im    = (const float*)d_in[9];
    const float* Dp      = (const float*)d_in[10];
    const float* out_W   = (const float*)d_in[11];
    const float* out_b   = (const float*)d_in[12];
    const float* ln_wr   = (const float*)d_in[13];
    const float* ln_br   = (const float*)d_in[14];
    const float* ln_wi   = (const float*)d_in[15];
    const float* ln_bi   = (const float*)d_in[16];
    const float* dec_Wr  = (const float*)d_in[17];
    const float* dec_Wi  = (const float*)d_in[18];
    const float* dec_br  = (const float*)d_in[19];
    const float* dec_bi  = (const float*)d_in[20];
    float* outp = (float*)d_out;

    const size_t NBHL = (size_t)B_ * H_ * L_;        // 8,388,608
    float* ws = (float*)d_ws;
    float* XR  = ws;
    float* XI  = XR + NBHL;
    float* ZRb = XI + NBHL;
    float* ZIb = ZRb + NBHL;
    float* G   = ZIb + NBHL;                         // gated GLU out, B*H*L
    float* Wt  = G + NBHL;                           // H*N*2
    float* Ct2t = Wt + H_ * N_ * 2;
    float* Kt  = Ct2t + H_ * N_ * 2;                 // H*128

    dim3 gEnc(32, 8, 4);
    enc_gemm<<<gEnc, 256, 0, stream>>>(x, enc_Wr, enc_Wi, enc_br, enc_bi, XR, XI);

    for (int i = 0; i < NL_; ++i) {
        precompute_kernel<<<dim3(H_), 64, 0, stream>>>(log_dt, A_re_log, A_im,
                                                       C_re, C_im, Wt, Ct2t, Kt, i);
        scan_kernel<<<dim3(B_ * H_), 256, 0, stream>>>(XR, XI, ZRb, ZIb, Wt, Ct2t, Kt,
                                                       Dp + (size_t)i * H_);
        // channel r
        glu_gemm_mfma<<<dim3(32, 8, 4), 256, 0, stream>>>(out_W + (size_t)i * 512 * 256,
                                                          out_b + (size_t)i * 512, ZRb, G);
        act_ln<<<dim3(128, 8), 256, 0, stream>>>(G, XR, ln_wr + (size_t)i * H_,
                                                 ln_br + (size_t)i * H_);
        // channel i
        glu_gemm_mfma<<<dim3(32, 8, 4), 256, 0, stream>>>(out_W + (size_t)i * 512 * 256,
                                                          out_b + (size_t)i * 512, ZIb, G);
        act_ln<<<dim3(128, 8), 256, 0, stream>>>(G, XI, ln_wi + (size_t)i * H_,
                                                 ln_bi + (size_t)i * H_);
    }

    dec_gemm<<<dim3(32, 8, 4), 256, 0, stream>>>(XR, XI, dec_Wr, dec_Wi,
                                                 dec_br, dec_bi, outp);
}